// Round 4
// baseline (1705.235 us; speedup 1.0000x reference)
//
#include <hip/hip_runtime.h>

#define NNODES 100000
#define NGRAPHS 512
#define D 128
#define OUTC 64
#define NEDGES 1600000

// ---------------- CSR build ----------------

__global__ void k_deg(const int* __restrict__ dst, int* __restrict__ deg, int E) {
    int e = blockIdx.x * 256 + threadIdx.x;
    if (e < E) atomicAdd(&deg[dst[e]], 1);
}

__global__ __launch_bounds__(1024) void k_scan(const int* __restrict__ deg,
                                               int* __restrict__ off, int N) {
    __shared__ int sm[1024];
    __shared__ int carry_sm;
    int t = threadIdx.x;
    if (t == 0) carry_sm = 0;
    __syncthreads();
    for (int base = 0; base < N; base += 1024) {
        int v = (base + t < N) ? deg[base + t] : 0;
        sm[t] = v;
        __syncthreads();
        #pragma unroll
        for (int ofs = 1; ofs < 1024; ofs <<= 1) {
            int add = (t >= ofs) ? sm[t - ofs] : 0;
            __syncthreads();
            sm[t] += add;
            __syncthreads();
        }
        int total = sm[1023];
        int carry = carry_sm;
        if (base + t < N) off[base + t] = carry + sm[t] - v;  // exclusive
        __syncthreads();
        if (t == 0) carry_sm = carry + total;
        __syncthreads();
    }
    if (t == 0) off[N] = carry_sm;
}

__global__ void k_fill(const int* __restrict__ src, const int* __restrict__ dst,
                       const int* __restrict__ off, int* __restrict__ cur,
                       int* __restrict__ csr, int E) {
    int e = blockIdx.x * 256 + threadIdx.x;
    if (e < E) {
        int d = dst[e];
        int p = off[d] + atomicAdd(&cur[d], 1);
        csr[p] = src[e];
    }
}

// ---------------- fused GIN layer: agg + (x+agg)@W + b, relu ----------------
// block = 256 threads = 4 waves, handles 32 nodes.
// Phase 1: wave w aggregates nodes w*8..w*8+7; lane holds float2 of the row.
//          Neighbor loop unrolled x8 with masked tail -> 8 loads in flight.
// Phase 2: register-tiled GEMM, thread = 4 nodes x 4 cols, W staged in 4
//          chunks of 32 rows (16 KB) -> total LDS 33.4 KB -> 4 blocks/CU.

template <int POOL>
__global__ __launch_bounds__(256, 4) void k_layer(
    const float* __restrict__ xin, const int* __restrict__ off,
    const int* __restrict__ csr, const float* __restrict__ W,
    const float* __restrict__ bias, float* __restrict__ hout,
    const int* __restrict__ batch, float* __restrict__ pooled) {
    __shared__ float Wl[32 * 128];    // 16 KB: quarter of W
    __shared__ float inl[32 * 132];   // 16.9 KB: padded (stride 132, 16B aligned)

    int t = threadIdx.x;
    int lane = t & 63;
    int wv = t >> 6;
    int n0 = blockIdx.x * 32;

    // ---- Phase 1: aggregation (8-deep MLP) ----
    for (int i = 0; i < 8; ++i) {
        int ln = wv * 8 + i;
        int n = n0 + ln;
        int o0 = off[n], o1 = off[n + 1];
        float2 acc = *(const float2*)(xin + (size_t)n * D + lane * 2);  // self
        for (int j0 = o0; j0 < o1; j0 += 64) {
            int cnt = o1 - j0;
            if (cnt > 64) cnt = 64;
            int sid = (j0 + lane < o1) ? csr[j0 + lane] : 0;
            for (int j = 0; j < cnt; j += 8) {
                int s[8];
                float m[8];
                #pragma unroll
                for (int k = 0; k < 8; ++k) {
                    int jj = j + k;
                    s[k] = __shfl(sid, jj < cnt ? jj : 0);  // clamp: lane 0 safe
                    m[k] = (jj < cnt) ? 1.f : 0.f;
                }
                float2 v[8];
                #pragma unroll
                for (int k = 0; k < 8; ++k)
                    v[k] = *(const float2*)(xin + (size_t)s[k] * D + lane * 2);
                #pragma unroll
                for (int k = 0; k < 8; ++k) {
                    acc.x = fmaf(v[k].x, m[k], acc.x);
                    acc.y = fmaf(v[k].y, m[k], acc.y);
                }
            }
        }
        *(float2*)(inl + ln * 132 + lane * 2) = acc;
    }

    // ---- Phase 2: GEMM ----
    int ng = t >> 5;  // 0..7 -> nodes ng*4..ng*4+3
    int cg = t & 31;  // 0..31 -> cols cg*4..cg*4+3
    float4 bv = *(const float4*)(bias + cg * 4);
    float acc[4][4];
    #pragma unroll
    for (int i = 0; i < 4; ++i) {
        acc[i][0] = bv.x; acc[i][1] = bv.y; acc[i][2] = bv.z; acc[i][3] = bv.w;
    }

    for (int q = 0; q < 4; ++q) {
        __syncthreads();  // q==0: inl ready; q>0: previous Wl reads done
        for (int idx = t; idx < 32 * 32; idx += 256) {
            int r = idx >> 5, c4 = idx & 31;
            *(float4*)(Wl + r * 128 + c4 * 4) =
                *(const float4*)(W + (size_t)(q * 32 + r) * 128 + c4 * 4);
        }
        __syncthreads();
        #pragma unroll
        for (int k4 = 0; k4 < 8; ++k4) {
            int k = k4 * 4;
            float4 w0 = *(const float4*)(Wl + (k + 0) * 128 + cg * 4);
            float4 w1 = *(const float4*)(Wl + (k + 1) * 128 + cg * 4);
            float4 w2 = *(const float4*)(Wl + (k + 2) * 128 + cg * 4);
            float4 w3 = *(const float4*)(Wl + (k + 3) * 128 + cg * 4);
            #pragma unroll
            for (int i = 0; i < 4; ++i) {
                float4 xv = *(const float4*)(inl + (ng * 4 + i) * 132 + q * 32 + k);
                acc[i][0] += xv.x * w0.x + xv.y * w1.x + xv.z * w2.x + xv.w * w3.x;
                acc[i][1] += xv.x * w0.y + xv.y * w1.y + xv.z * w2.y + xv.w * w3.y;
                acc[i][2] += xv.x * w0.z + xv.y * w1.z + xv.z * w2.z + xv.w * w3.z;
                acc[i][3] += xv.x * w0.w + xv.y * w1.w + xv.z * w2.w + xv.w * w3.w;
            }
        }
    }

    if (POOL) {
        #pragma unroll
        for (int i = 0; i < 4; ++i) {
            int n = n0 + ng * 4 + i;
            int g = batch[n];
            float* p = pooled + (size_t)g * D + cg * 4;
            #pragma unroll
            for (int j = 0; j < 4; ++j) {
                float v = fmaxf(acc[i][j], 0.f);
                unsafeAtomicAdd(p + j, v);
            }
        }
    } else {
        #pragma unroll
        for (int i = 0; i < 4; ++i) {
            int n = n0 + ng * 4 + i;
            float4 o;
            o.x = fmaxf(acc[i][0], 0.f);
            o.y = fmaxf(acc[i][1], 0.f);
            o.z = fmaxf(acc[i][2], 0.f);
            o.w = fmaxf(acc[i][3], 0.f);
            *(float4*)(hout + (size_t)n * D + cg * 4) = o;
        }
    }
}

// ---------------- pooling counts + final FC ----------------

__global__ void k_count(const int* __restrict__ batch, int* __restrict__ cnt, int N) {
    int i = blockIdx.x * 256 + threadIdx.x;
    if (i < N) atomicAdd(&cnt[batch[i]], 1);
}

__global__ __launch_bounds__(64) void k_fc(const float* __restrict__ pooled,
                                           const int* __restrict__ cnt,
                                           const float* __restrict__ Wfc,
                                           const float* __restrict__ bfc,
                                           float* __restrict__ out) {
    __shared__ float row[128];
    int g = blockIdx.x, o = threadIdx.x;
    float inv = 1.f / fmaxf((float)cnt[g], 1.f);
    row[o] = pooled[(size_t)g * D + o] * inv;
    row[o + 64] = pooled[(size_t)g * D + o + 64] * inv;
    __syncthreads();
    float a = bfc[o];
    #pragma unroll 8
    for (int k = 0; k < 128; ++k) a += row[k] * Wfc[k * OUTC + o];
    out[(size_t)g * OUTC + o] = a;
}

// ---------------- launch ----------------

extern "C" void kernel_launch(void* const* d_in, const int* in_sizes, int n_in,
                              void* d_out, int out_size, void* d_ws, size_t ws_size,
                              hipStream_t stream) {
    const float* x = (const float*)d_in[0];
    const int* ei = (const int*)d_in[1];
    const int* batch = (const int*)d_in[2];
    const float* W1 = (const float*)d_in[3];
    const float* b1 = (const float*)d_in[4];
    const float* W2 = (const float*)d_in[5];
    const float* b2 = (const float*)d_in[6];
    const float* W3 = (const float*)d_in[7];
    const float* b3 = (const float*)d_in[8];
    const float* Wfc = (const float*)d_in[9];
    const float* bfc = (const float*)d_in[10];
    float* out = (float*)d_out;

    const int* src = ei;             // edge_index[0]
    const int* dst = ei + NEDGES;    // edge_index[1]

    char* ws = (char*)d_ws;
    size_t P = 0;
    auto alloc = [&](size_t bytes) {
        size_t r = P;
        P += (bytes + 255) & ~(size_t)255;
        return r;
    };
    int* off = (int*)(ws + alloc((NNODES + 1) * 4));
    int* deg = (int*)(ws + alloc(NNODES * 4));
    int* cur = (int*)(ws + alloc(NNODES * 4));
    int* csr = (int*)(ws + alloc((size_t)NEDGES * 4));
    float* bufA = (float*)(ws + alloc((size_t)NNODES * D * 4));
    float* bufB = (float*)(ws + alloc((size_t)NNODES * D * 4));
    float* pooled = (float*)(ws + alloc((size_t)NGRAPHS * D * 4));
    int* cnt = (int*)(ws + alloc(NGRAPHS * 4));

    hipMemsetAsync(deg, 0, NNODES * 4, stream);
    hipMemsetAsync(cur, 0, NNODES * 4, stream);
    hipMemsetAsync(pooled, 0, NGRAPHS * D * 4, stream);
    hipMemsetAsync(cnt, 0, NGRAPHS * 4, stream);

    k_deg<<<NEDGES / 256, 256, 0, stream>>>(dst, deg, NEDGES);
    k_scan<<<1, 1024, 0, stream>>>(deg, off, NNODES);
    k_fill<<<NEDGES / 256, 256, 0, stream>>>(src, dst, off, cur, csr, NEDGES);

    k_layer<0><<<NNODES / 32, 256, 0, stream>>>(x, off, csr, W1, b1, bufA, nullptr, nullptr);
    k_layer<0><<<NNODES / 32, 256, 0, stream>>>(bufA, off, csr, W2, b2, bufB, nullptr, nullptr);
    k_layer<1><<<NNODES / 32, 256, 0, stream>>>(bufB, off, csr, W3, b3, nullptr, batch, pooled);

    k_count<<<(NNODES + 255) / 256, 256, 0, stream>>>(batch, cnt, NNODES);
    k_fc<<<NGRAPHS, 64, 0, stream>>>(pooled, cnt, Wfc, bfc, out);
}

// Round 5
// 1079.266 us; speedup vs baseline: 1.5800x; 1.5800x over previous
//
#include <hip/hip_runtime.h>

#define NNODES 100000
#define NGRAPHS 512
#define D 128
#define OUTC 64
#define NEDGES 1600000

// ---------------- CSR build ----------------

__global__ void k_deg(const int* __restrict__ dst, int* __restrict__ deg, int E) {
    int e = blockIdx.x * 256 + threadIdx.x;
    if (e < E) atomicAdd(&deg[dst[e]], 1);
}

__global__ __launch_bounds__(1024) void k_scan(const int* __restrict__ deg,
                                               int* __restrict__ off, int N) {
    __shared__ int sm[1024];
    __shared__ int carry_sm;
    int t = threadIdx.x;
    if (t == 0) carry_sm = 0;
    __syncthreads();
    for (int base = 0; base < N; base += 1024) {
        int v = (base + t < N) ? deg[base + t] : 0;
        sm[t] = v;
        __syncthreads();
        #pragma unroll
        for (int ofs = 1; ofs < 1024; ofs <<= 1) {
            int add = (t >= ofs) ? sm[t - ofs] : 0;
            __syncthreads();
            sm[t] += add;
            __syncthreads();
        }
        int total = sm[1023];
        int carry = carry_sm;
        if (base + t < N) off[base + t] = carry + sm[t] - v;  // exclusive
        __syncthreads();
        if (t == 0) carry_sm = carry + total;
        __syncthreads();
    }
    if (t == 0) off[N] = carry_sm;
}

__global__ void k_fill(const int* __restrict__ src, const int* __restrict__ dst,
                       const int* __restrict__ off, int* __restrict__ cur,
                       int* __restrict__ csr, int E) {
    int e = blockIdx.x * 256 + threadIdx.x;
    if (e < E) {
        int d = dst[e];
        int p = off[d] + atomicAdd(&cur[d], 1);
        csr[p] = src[e];
    }
}

// ---------------- aggregation: agg[n] = x[n] + sum_{s in N(n)} x[s] ----------
// thread = (node n = gid>>5, cols c = (gid&31)*4). One float4 per neighbor per
// thread, 32 threads/row -> every load is a fully-coalesced 512B row read.
// 8-deep unroll with clamp+mask -> 8 independent loads in flight per lane.

__global__ __launch_bounds__(256, 6) void k_agg(
    const float* __restrict__ x, const int* __restrict__ off,
    const int* __restrict__ csr, float* __restrict__ agg) {
    int gid = blockIdx.x * 256 + threadIdx.x;
    int n = gid >> 5;
    if (n >= NNODES) return;
    int c = (gid & 31) << 2;  // float offset in row

    float4 acc = *(const float4*)(x + (size_t)n * D + c);  // self term
    int o0 = off[n], o1 = off[n + 1];

    for (int j = o0; j < o1; j += 8) {
        int idx[8];
        float m[8];
        #pragma unroll
        for (int k = 0; k < 8; ++k) {
            int jj = j + k;
            bool ok = jj < o1;
            idx[k] = ok ? csr[jj] : n;  // clamp to own row (valid addr)
            m[k] = ok ? 1.f : 0.f;
        }
        float4 v[8];
        #pragma unroll
        for (int k = 0; k < 8; ++k)
            v[k] = *(const float4*)(x + (size_t)idx[k] * D + c);
        #pragma unroll
        for (int k = 0; k < 8; ++k) {
            acc.x = fmaf(v[k].x, m[k], acc.x);
            acc.y = fmaf(v[k].y, m[k], acc.y);
            acc.z = fmaf(v[k].z, m[k], acc.z);
            acc.w = fmaf(v[k].w, m[k], acc.w);
        }
    }
    *(float4*)(agg + (size_t)n * D + c) = acc;
}

// ---------------- GEMM: h = relu(agg @ W + b), [N x 128] @ [128 x 128] ------
// block = 256 threads, tile 64 nodes x 128 cols; thread = 8 nodes x 4 cols.

__global__ __launch_bounds__(256, 4) void k_gemm(
    const float* __restrict__ xin, const float* __restrict__ W,
    const float* __restrict__ bias, float* __restrict__ hout) {
    __shared__ float xs[64 * 132];  // 33.8 KB, padded stride
    __shared__ float Wl[32 * 128];  // 16 KB, quarter of W

    int t = threadIdx.x;
    int n0 = blockIdx.x * 64;

    for (int i = t; i < 64 * 32; i += 256) {
        int r = i >> 5, c4 = i & 31;
        int n = n0 + r;
        if (n > NNODES - 1) n = NNODES - 1;  // clamp (last block)
        *(float4*)(xs + r * 132 + c4 * 4) =
            *(const float4*)(xin + (size_t)n * D + c4 * 4);
    }

    int cg = t & 31;  // 4-col group
    int ng = t >> 5;  // node group of 8
    float4 bv = *(const float4*)(bias + cg * 4);
    float acc[8][4];
    #pragma unroll
    for (int i = 0; i < 8; ++i) {
        acc[i][0] = bv.x; acc[i][1] = bv.y; acc[i][2] = bv.z; acc[i][3] = bv.w;
    }

    for (int q = 0; q < 4; ++q) {
        __syncthreads();  // q==0: xs ready; q>0: previous Wl reads done
        for (int i = t; i < 32 * 32; i += 256) {
            int r = i >> 5, c4 = i & 31;
            *(float4*)(Wl + r * 128 + c4 * 4) =
                *(const float4*)(W + (size_t)(q * 32 + r) * D + c4 * 4);
        }
        __syncthreads();
        #pragma unroll
        for (int k4 = 0; k4 < 8; ++k4) {
            float4 w0 = *(const float4*)(Wl + (k4 * 4 + 0) * 128 + cg * 4);
            float4 w1 = *(const float4*)(Wl + (k4 * 4 + 1) * 128 + cg * 4);
            float4 w2 = *(const float4*)(Wl + (k4 * 4 + 2) * 128 + cg * 4);
            float4 w3 = *(const float4*)(Wl + (k4 * 4 + 3) * 128 + cg * 4);
            #pragma unroll
            for (int i = 0; i < 8; ++i) {
                float4 xv = *(const float4*)(xs + (ng * 8 + i) * 132 + q * 32 + k4 * 4);
                acc[i][0] += xv.x * w0.x + xv.y * w1.x + xv.z * w2.x + xv.w * w3.x;
                acc[i][1] += xv.x * w0.y + xv.y * w1.y + xv.z * w2.y + xv.w * w3.y;
                acc[i][2] += xv.x * w0.z + xv.y * w1.z + xv.z * w2.z + xv.w * w3.z;
                acc[i][3] += xv.x * w0.w + xv.y * w1.w + xv.z * w2.w + xv.w * w3.w;
            }
        }
    }

    #pragma unroll
    for (int i = 0; i < 8; ++i) {
        int n = n0 + ng * 8 + i;
        if (n < NNODES) {
            float4 o;
            o.x = fmaxf(acc[i][0], 0.f);
            o.y = fmaxf(acc[i][1], 0.f);
            o.z = fmaxf(acc[i][2], 0.f);
            o.w = fmaxf(acc[i][3], 0.f);
            *(float4*)(hout + (size_t)n * D + cg * 4) = o;
        }
    }
}

// ---------------- graph offsets from sorted batch ----------------

__global__ void k_goff(const int* __restrict__ batch, int* __restrict__ goff, int N) {
    int i = blockIdx.x * 256 + threadIdx.x;
    if (i >= N) return;
    int b = batch[i];
    if (i == 0) {
        for (int g = 0; g <= b; ++g) goff[g] = 0;
    } else {
        int p = batch[i - 1];
        for (int g = p + 1; g <= b; ++g) goff[g] = i;
    }
    if (i == N - 1) {
        for (int g = b + 1; g <= NGRAPHS; ++g) goff[g] = N;
    }
}

// ---------------- mean pool: one block per graph ----------------

__global__ __launch_bounds__(128) void k_pool(const float* __restrict__ h,
                                              const int* __restrict__ goff,
                                              float* __restrict__ pooled) {
    int g = blockIdx.x, c = threadIdx.x;
    int s = goff[g], e = goff[g + 1];
    float a = 0.f;
    int n = s;
    for (; n + 4 <= e; n += 4) {
        float v0 = h[(size_t)(n + 0) * D + c];
        float v1 = h[(size_t)(n + 1) * D + c];
        float v2 = h[(size_t)(n + 2) * D + c];
        float v3 = h[(size_t)(n + 3) * D + c];
        a += (v0 + v1) + (v2 + v3);
    }
    for (; n < e; ++n) a += h[(size_t)n * D + c];
    pooled[(size_t)g * D + c] = a / fmaxf((float)(e - s), 1.f);
}

// ---------------- final FC ----------------

__global__ __launch_bounds__(64) void k_fc(const float* __restrict__ pooled,
                                           const float* __restrict__ Wfc,
                                           const float* __restrict__ bfc,
                                           float* __restrict__ out) {
    __shared__ float row[128];
    int g = blockIdx.x, o = threadIdx.x;
    row[o] = pooled[(size_t)g * D + o];
    row[o + 64] = pooled[(size_t)g * D + o + 64];
    __syncthreads();
    float a = bfc[o];
    #pragma unroll 8
    for (int k = 0; k < 128; ++k) a += row[k] * Wfc[k * OUTC + o];
    out[(size_t)g * OUTC + o] = a;
}

// ---------------- launch ----------------

extern "C" void kernel_launch(void* const* d_in, const int* in_sizes, int n_in,
                              void* d_out, int out_size, void* d_ws, size_t ws_size,
                              hipStream_t stream) {
    const float* x = (const float*)d_in[0];
    const int* ei = (const int*)d_in[1];
    const int* batch = (const int*)d_in[2];
    const float* W1 = (const float*)d_in[3];
    const float* b1 = (const float*)d_in[4];
    const float* W2 = (const float*)d_in[5];
    const float* b2 = (const float*)d_in[6];
    const float* W3 = (const float*)d_in[7];
    const float* b3 = (const float*)d_in[8];
    const float* Wfc = (const float*)d_in[9];
    const float* bfc = (const float*)d_in[10];
    float* out = (float*)d_out;

    const int* src = ei;           // edge_index[0]
    const int* dst = ei + NEDGES;  // edge_index[1]

    char* ws = (char*)d_ws;
    size_t P = 0;
    auto alloc = [&](size_t bytes) {
        size_t r = P;
        P += (bytes + 255) & ~(size_t)255;
        return r;
    };
    int* off = (int*)(ws + alloc((NNODES + 1) * 4));
    int* deg = (int*)(ws + alloc(NNODES * 4));
    int* cur = (int*)(ws + alloc(NNODES * 4));
    int* csr = (int*)(ws + alloc((size_t)(NEDGES + 64) * 4));  // +pad for masked reads
    float* bufA = (float*)(ws + alloc((size_t)NNODES * D * 4));
    float* bufB = (float*)(ws + alloc((size_t)NNODES * D * 4));
    float* pooled = (float*)(ws + alloc((size_t)NGRAPHS * D * 4));
    int* goff = (int*)(ws + alloc((NGRAPHS + 1) * 4));

    hipMemsetAsync(deg, 0, NNODES * 4, stream);
    hipMemsetAsync(cur, 0, NNODES * 4, stream);

    k_deg<<<NEDGES / 256, 256, 0, stream>>>(dst, deg, NEDGES);
    k_scan<<<1, 1024, 0, stream>>>(deg, off, NNODES);
    k_fill<<<NEDGES / 256, 256, 0, stream>>>(src, dst, off, cur, csr, NEDGES);
    k_goff<<<(NNODES + 255) / 256, 256, 0, stream>>>(batch, goff, NNODES);

    const int AGG_GRID = (NNODES * 32 + 255) / 256;
    const int GEMM_GRID = (NNODES + 63) / 64;

    // layer 1: agg(x)->bufB, gemm(bufB)->bufA
    k_agg<<<AGG_GRID, 256, 0, stream>>>(x, off, csr, bufB);
    k_gemm<<<GEMM_GRID, 256, 0, stream>>>(bufB, W1, b1, bufA);
    // layer 2: agg(bufA)->bufB, gemm(bufB)->bufA
    k_agg<<<AGG_GRID, 256, 0, stream>>>(bufA, off, csr, bufB);
    k_gemm<<<GEMM_GRID, 256, 0, stream>>>(bufB, W2, b2, bufA);
    // layer 3: agg(bufA)->bufB, gemm(bufB)->bufA
    k_agg<<<AGG_GRID, 256, 0, stream>>>(bufA, off, csr, bufB);
    k_gemm<<<GEMM_GRID, 256, 0, stream>>>(bufB, W3, b3, bufA);

    k_pool<<<NGRAPHS, 128, 0, stream>>>(bufA, goff, pooled);
    k_fc<<<NGRAPHS, 64, 0, stream>>>(pooled, Wfc, bfc, out);
}